// Round 1
// baseline (254.361 us; speedup 1.0000x reference)
//
#include <hip/hip_runtime.h>
#include <hip/hip_fp16.h>

// Problem: QuantizedLinearWhisper — E2M1 block-32 fake-quant of x and W, then x_q @ W_q^T + bias.
// M=12000 (8*1500), K=1280, N=5120. Outputs: out[12000][5120] fp32, scale_w[5120][40] fp32.
//
// Strategy: bit-exact replication of the reference quantization in fp32 (same op order:
// amax/6.0 division, v/scale division, strict > bounds, sign*level*scale), stored as fp16
// into d_ws; then m97-structure 128x128 MFMA GEMM (BK=32, global_load_lds width=16,
// mfma_f32_16x16x32_f16). fp16 rounding error ~2e-3 absmax vs 0.08 threshold.

typedef _Float16 f16;
typedef _Float16 f16x8 __attribute__((ext_vector_type(8)));
typedef float f32x4 __attribute__((ext_vector_type(4)));

#define M_ROWS 12000
#define M_PAD  12032
#define N_COLS 5120
#define K_DIM  1280
#define KB     40      // 1280/32 blocks per row

// ---- E2M1 nearest-level (strict > boundaries, identical to reference) ----
__device__ __forceinline__ float e2m1_level(float a) {
    float lv;
    if (a > 2.5f)       lv = (a > 3.5f) ? ((a > 5.0f) ? 6.0f : 4.0f) : 3.0f;
    else if (a > 1.25f) lv = (a > 1.75f) ? 2.0f : 1.5f;
    else                lv = (a > 0.75f) ? 1.0f : ((a > 0.25f) ? 0.5f : 0.0f);
    return lv;
}

// ---- quantize x: [12000][1280] fp32 -> [12032][1280] fp16 (pad rows zero) ----
// Each thread handles 8 consecutive elements; 4 threads = one 32-block; amax via shfl_xor.
__global__ __launch_bounds__(256) void quant_x_kernel(const float* __restrict__ x,
                                                      f16* __restrict__ xq) {
    int t = blockIdx.x * blockDim.x + threadIdx.x;   // 12032*160 threads
    int row = t / 160;
    int c8  = t % 160;
    f16x8 o;
    if (row < M_ROWS) {
        const float* p = x + (size_t)row * K_DIM + c8 * 8;
        float v[8];
        *(float4*)&v[0] = *(const float4*)p;
        *(float4*)&v[4] = *(const float4*)(p + 4);
        float am = 0.0f;
        #pragma unroll
        for (int i = 0; i < 8; ++i) am = fmaxf(am, fabsf(v[i]));
        am = fmaxf(am, __shfl_xor(am, 1));
        am = fmaxf(am, __shfl_xor(am, 2));
        float scale = fmaxf(am / 6.0f, 1e-12f);
        #pragma unroll
        for (int i = 0; i < 8; ++i) {
            float tq = v[i] / scale;
            float q  = copysignf(e2m1_level(fabsf(tq)), tq) * scale;
            o[i] = (f16)q;
        }
    } else {
        #pragma unroll
        for (int i = 0; i < 8; ++i) o[i] = (f16)0.0f;
    }
    *(f16x8*)(xq + (size_t)row * K_DIM + c8 * 8) = o;
}

// ---- quantize W: [5120][1280] fp32 -> fp16 + scale_w[5120][40] fp32 ----
__global__ __launch_bounds__(256) void quant_w_kernel(const float* __restrict__ w,
                                                      f16* __restrict__ wq,
                                                      float* __restrict__ scale_out) {
    int t = blockIdx.x * blockDim.x + threadIdx.x;   // 5120*160 threads
    int row = t / 160;
    int c8  = t % 160;
    const float* p = w + (size_t)row * K_DIM + c8 * 8;
    float v[8];
    *(float4*)&v[0] = *(const float4*)p;
    *(float4*)&v[4] = *(const float4*)(p + 4);
    float am = 0.0f;
    #pragma unroll
    for (int i = 0; i < 8; ++i) am = fmaxf(am, fabsf(v[i]));
    am = fmaxf(am, __shfl_xor(am, 1));
    am = fmaxf(am, __shfl_xor(am, 2));
    float scale = fmaxf(am / 6.0f, 1e-12f);
    if ((t & 3) == 0) scale_out[row * KB + (c8 >> 2)] = scale;
    f16x8 o;
    #pragma unroll
    for (int i = 0; i < 8; ++i) {
        float tq = v[i] / scale;
        float q  = copysignf(e2m1_level(fabsf(tq)), tq) * scale;
        o[i] = (f16)q;
    }
    *(f16x8*)(wq + (size_t)row * K_DIM + c8 * 8) = o;
}

// ---- GEMM: C[M][N] = A[Mpad][K] * B[N][K]^T + bias, m97 structure ----
// 128x128 tile, BK=32, 256 threads (4 waves, 2x2), 16x mfma_f32_16x16x32_f16 per wave/K-step.
#define BM 128
#define BN 128
#define BK 32

__global__ __launch_bounds__(256) void gemm_kernel(const f16* __restrict__ A,
                                                   const f16* __restrict__ B,
                                                   const float* __restrict__ bias,
                                                   float* __restrict__ C) {
    __shared__ f16 lA[BM * BK];   // 8 KB
    __shared__ f16 lB[BN * BK];   // 8 KB

    int bid = blockIdx.x;
    // XCD-aware swizzle: grid = 3760 = 8 * 470 (divisible -> simple form is bijective)
    int swz = (bid & 7) * 470 + (bid >> 3);
    int mt = swz / 40;            // 94 m-tiles
    int nt = swz % 40;            // 40 n-tiles

    int tid  = threadIdx.x;
    int lane = tid & 63;
    int wid  = tid >> 6;
    int wr   = wid >> 1;          // wave row (0..1)
    int wc   = wid & 1;           // wave col (0..1)

    const int rowA0 = mt * BM;
    const int colB0 = nt * BN;

    f32x4 acc[4][4] = {};

    for (int k0 = 0; k0 < K_DIM; k0 += BK) {
        // stage A and B tiles: 512 chunks of 16B each per tile, 2 per thread per tile
        #pragma unroll
        for (int s = 0; s < 2; ++s) {
            int i  = s * 256 + wid * 64 + lane;   // chunk index [0,512)
            int r  = i >> 2;                       // tile row
            int c8 = i & 3;                        // which 8-elem group in the 32-wide row
            const f16* gpA = A + (size_t)(rowA0 + r) * K_DIM + k0 + c8 * 8;
            const f16* gpB = B + (size_t)(colB0 + r) * K_DIM + k0 + c8 * 8;
            f16* lpA = lA + (i << 3);              // linear LDS, lane-contiguous
            f16* lpB = lB + (i << 3);
            __builtin_amdgcn_global_load_lds(
                (const __attribute__((address_space(1))) unsigned*)gpA,
                (__attribute__((address_space(3))) unsigned*)lpA, 16, 0, 0);
            __builtin_amdgcn_global_load_lds(
                (const __attribute__((address_space(1))) unsigned*)gpB,
                (__attribute__((address_space(3))) unsigned*)lpB, 16, 0, 0);
        }
        __syncthreads();   // compiler drains vmcnt+lgkmcnt before barrier

        f16x8 af[4], bf[4];
        #pragma unroll
        for (int m = 0; m < 4; ++m)
            af[m] = *(const f16x8*)&lA[(wr * 64 + m * 16 + (lane & 15)) * BK + (lane >> 4) * 8];
        #pragma unroll
        for (int n = 0; n < 4; ++n)
            bf[n] = *(const f16x8*)&lB[(wc * 64 + n * 16 + (lane & 15)) * BK + (lane >> 4) * 8];

        #pragma unroll
        for (int m = 0; m < 4; ++m)
            #pragma unroll
            for (int n = 0; n < 4; ++n)
                acc[m][n] = __builtin_amdgcn_mfma_f32_16x16x32_f16(af[m], bf[n], acc[m][n], 0, 0, 0);

        __syncthreads();
    }

    // epilogue: C/D layout col = lane&15, row = (lane>>4)*4 + j  [m89-verified]
    int crow0 = rowA0 + wr * 64;
    int ccol0 = colB0 + wc * 64;
    float bz[4];
    #pragma unroll
    for (int n = 0; n < 4; ++n) bz[n] = bias[ccol0 + n * 16 + (lane & 15)];

    #pragma unroll
    for (int m = 0; m < 4; ++m) {
        #pragma unroll
        for (int j = 0; j < 4; ++j) {
            int row = crow0 + m * 16 + (lane >> 4) * 4 + j;
            if (row < M_ROWS) {
                float* cp = C + (size_t)row * N_COLS + ccol0 + (lane & 15);
                #pragma unroll
                for (int n = 0; n < 4; ++n)
                    cp[n * 16] = acc[m][n][j] + bz[n];
            }
        }
    }
}

extern "C" void kernel_launch(void* const* d_in, const int* in_sizes, int n_in,
                              void* d_out, int out_size, void* d_ws, size_t ws_size,
                              hipStream_t stream) {
    const float* x      = (const float*)d_in[0];
    const float* weight = (const float*)d_in[1];
    const float* bias   = (const float*)d_in[2];
    float* out     = (float*)d_out;                         // [12000][5120]
    float* scale_w = (float*)d_out + (size_t)M_ROWS * N_COLS; // [5120][40]

    // workspace layout: xq fp16 [12032][1280] then wq fp16 [5120][1280]  (~44 MB)
    f16* xq = (f16*)d_ws;
    f16* wq = (f16*)((char*)d_ws + (size_t)M_PAD * K_DIM * sizeof(f16));

    {
        int threads = M_PAD * (K_DIM / 8);
        quant_x_kernel<<<threads / 256, 256, 0, stream>>>(x, xq);
    }
    {
        int threads = N_COLS * (K_DIM / 8);
        quant_w_kernel<<<threads / 256, 256, 0, stream>>>(weight, wq, scale_w);
    }
    {
        int grid = (M_PAD / BM) * (N_COLS / BN);   // 94*40 = 3760
        gemm_kernel<<<grid, 256, 0, stream>>>(xq, wq, bias, out);
    }
}